// Round 1
// baseline (359.007 us; speedup 1.0000x reference)
//
#include <hip/hip_runtime.h>

namespace {

constexpr int kB = 8;
constexpr int kCH = 256;
constexpr int kN = 2048;
constexpr int QBLK = 64;
constexpr int KVBLK = 64;
constexpr int NWAVE = 4;
constexpr int KS_STRIDE = kCH + 8;    // 264 f16 = 528 B rows (pad kills pow2 stride)
constexpr int VS_STRIDE = KVBLK + 8;  // 72 f16  = 144 B rows
constexpr int PS_STRIDE = KVBLK + 8;  // 72

typedef _Float16 f16x8 __attribute__((ext_vector_type(8)));
typedef _Float16 f16x4 __attribute__((ext_vector_type(4)));
typedef float f32x4 __attribute__((ext_vector_type(4)));

__global__ __launch_bounds__(256, 1) void attn_fwd(
    const float* __restrict__ kg, const float* __restrict__ qg,
    const float* __restrict__ vg, float* __restrict__ og)
{
  // LDS: K chunk transposed to [m][c] (8-contig c reads for QK B-frags),
  //      V chunk transposed to [c][m] (8-contig m reads for PV A-frags),
  //      P per-wave [n][m] (8-contig m reads for PV B-frags).
  __shared__ alignas(16) _Float16 Ks[KVBLK][KS_STRIDE];
  __shared__ alignas(16) _Float16 Vs[kCH][VS_STRIDE];
  __shared__ alignas(16) _Float16 Ps[NWAVE][16][PS_STRIDE];
  __shared__ float red[NWAVE][16];

  const int tid = threadIdx.x;
  const int wv = tid >> 6;
  const int lane = tid & 63;
  const int s = lane & 15;   // col-part of lane
  const int qd = lane >> 4;  // quadrant

  // b = blockIdx%8: same-batch blocks land on the same XCD (round-robin
  // dispatch) so the batch's 4MB of K+V stays resident in that XCD's L2.
  const int b = blockIdx.x & 7;
  const int qt = blockIdx.x >> 3;
  const int n0w = qt * QBLK + wv * 16;  // this wave's 16 query rows

  const float* kb = kg + (size_t)b * kCH * kN;
  const float* qb = qg + (size_t)b * kN * kCH;
  const float* vb = vg + (size_t)b * kN * kCH;
  float* ob = og + (size_t)b * kCH * kN;

  // ---- Q fragments in registers: a[j] = Q[n0w+s][ks*32 + qd*8 + j]
  f16x8 qf[8];
  {
    const float* qrow = qb + (size_t)(n0w + s) * kCH + qd * 8;
#pragma unroll
    for (int ks = 0; ks < 8; ++ks) {
      f32x4 a = *(const f32x4*)(qrow + ks * 32);
      f32x4 c = *(const f32x4*)(qrow + ks * 32 + 4);
      f16x8 h;
      h[0] = (_Float16)a[0]; h[1] = (_Float16)a[1];
      h[2] = (_Float16)a[2]; h[3] = (_Float16)a[3];
      h[4] = (_Float16)c[0]; h[5] = (_Float16)c[1];
      h[6] = (_Float16)c[2]; h[7] = (_Float16)c[3];
      qf[ks] = h;
    }
  }

  // O^T accumulator: 16 c-tiles of 16x16; lane holds O^T[ct*16+qd*4+r][n0w+s]
  f32x4 acc[16];
#pragma unroll
  for (int i = 0; i < 16; ++i) acc[i] = f32x4{0.f, 0.f, 0.f, 0.f};
  float m_r[4] = {-1e30f, -1e30f, -1e30f, -1e30f};
  float l_r[4] = {0.f, 0.f, 0.f, 0.f};

  constexpr float SCALE = 0.0625f;  // 256^-0.5
  constexpr float LOG2E = 1.4426950408889634f;

  for (int kv0 = 0; kv0 < kN; kv0 += KVBLK) {
    __syncthreads();  // previous iteration's LDS reads complete

    // ---- stage K: Ks[m][c] = f16(k[b][c][kv0+m]); 4x4 register micro-transpose
    {
      const int m0 = 4 * (tid >> 4);
      const int c0b = 4 * (tid & 15);
#pragma unroll
      for (int p = 0; p < 4; ++p) {
        const int c0 = c0b + 64 * p;
        const float* src = kb + (size_t)c0 * kN + kv0 + m0;
        f32x4 r0 = *(const f32x4*)(src);
        f32x4 r1 = *(const f32x4*)(src + kN);
        f32x4 r2 = *(const f32x4*)(src + 2 * kN);
        f32x4 r3 = *(const f32x4*)(src + 3 * kN);
#pragma unroll
        for (int i = 0; i < 4; ++i) {
          f16x4 w;
          w[0] = (_Float16)r0[i]; w[1] = (_Float16)r1[i];
          w[2] = (_Float16)r2[i]; w[3] = (_Float16)r3[i];
          *(f16x4*)(&Ks[m0 + i][c0]) = w;
        }
      }
    }
    // ---- stage V: Vs[c][m] = f16(v[b][kv0+m][c]); same micro-transpose
    {
      const int m0 = 4 * (tid & 15);
      const int c0b = 4 * (tid >> 4);
#pragma unroll
      for (int p = 0; p < 4; ++p) {
        const int c0 = c0b + 64 * p;
        const float* src = vb + (size_t)(kv0 + m0) * kCH + c0;
        f32x4 r0 = *(const f32x4*)(src);
        f32x4 r1 = *(const f32x4*)(src + kCH);
        f32x4 r2 = *(const f32x4*)(src + 2 * kCH);
        f32x4 r3 = *(const f32x4*)(src + 3 * kCH);
#pragma unroll
        for (int i = 0; i < 4; ++i) {
          f16x4 w;
          w[0] = (_Float16)r0[i]; w[1] = (_Float16)r1[i];
          w[2] = (_Float16)r2[i]; w[3] = (_Float16)r3[i];
          *(f16x4*)(&Vs[c0 + i][m0]) = w;
        }
      }
    }
    __syncthreads();

    // ---- QK^T: S[16n x 64m], A=Q(reg), B=K(LDS)
    f32x4 sacc[4];
#pragma unroll
    for (int mc = 0; mc < 4; ++mc) sacc[mc] = f32x4{0.f, 0.f, 0.f, 0.f};
#pragma unroll
    for (int mc = 0; mc < 4; ++mc) {
#pragma unroll
      for (int ks = 0; ks < 8; ++ks) {
        f16x8 bf = *(const f16x8*)(&Ks[mc * 16 + s][ks * 32 + qd * 8]);
        sacc[mc] = __builtin_amdgcn_mfma_f32_16x16x32_f16(qf[ks], bf, sacc[mc], 0, 0, 0);
      }
    }

    // ---- online softmax. Lane holds S[row = qd*4+r][col = mc*16+s].
    float pmax[4];
#pragma unroll
    for (int r = 0; r < 4; ++r) {
      float mx = fmaxf(fmaxf(sacc[0][r], sacc[1][r]), fmaxf(sacc[2][r], sacc[3][r]));
      pmax[r] = mx;
    }
#pragma unroll
    for (int off = 1; off < 16; off <<= 1) {
#pragma unroll
      for (int r = 0; r < 4; ++r)
        pmax[r] = fmaxf(pmax[r], __shfl_xor(pmax[r], off, 64));
    }
    float corr[4], lsum[4];
#pragma unroll
    for (int r = 0; r < 4; ++r) {
      float mn = fmaxf(m_r[r], SCALE * pmax[r]);
      corr[r] = exp2f((m_r[r] - mn) * LOG2E);
      m_r[r] = mn;
      lsum[r] = 0.f;
    }
#pragma unroll
    for (int mc = 0; mc < 4; ++mc) {
#pragma unroll
      for (int r = 0; r < 4; ++r) {
        float pvf = exp2f((SCALE * sacc[mc][r] - m_r[r]) * LOG2E);
        lsum[r] += pvf;
        Ps[wv][qd * 4 + r][mc * 16 + s] = (_Float16)pvf;
      }
    }
#pragma unroll
    for (int off = 1; off < 16; off <<= 1) {
#pragma unroll
      for (int r = 0; r < 4; ++r) lsum[r] += __shfl_xor(lsum[r], off, 64);
    }
#pragma unroll
    for (int r = 0; r < 4; ++r) l_r[r] = l_r[r] * corr[r] + lsum[r];

    // redistribute rescale factor from row-owners to col(n)-indexed lanes
    if (s == 0) {
#pragma unroll
      for (int r = 0; r < 4; ++r) red[wv][qd * 4 + r] = corr[r];
    }
    asm volatile("s_waitcnt lgkmcnt(0)" ::: "memory");  // P + red visible wave-wide
    const float sc = red[wv][s];
#pragma unroll
    for (int i = 0; i < 16; ++i) acc[i] *= sc;

    // ---- PV as O^T += V^T @ P^T  (A=V from LDS, B=P from LDS, B reused over ct)
#pragma unroll
    for (int ms = 0; ms < 2; ++ms) {
      f16x8 pf = *(const f16x8*)(&Ps[wv][s][ms * 32 + qd * 8]);
#pragma unroll
      for (int ct = 0; ct < 16; ++ct) {
        f16x8 vf = *(const f16x8*)(&Vs[ct * 16 + s][ms * 32 + qd * 8]);
        acc[ct] = __builtin_amdgcn_mfma_f32_16x16x32_f16(vf, pf, acc[ct], 0, 0, 0);
      }
    }
  }

  // ---- epilogue: normalize and store O^T (coalesced along n)
  if (s == 0) {
#pragma unroll
    for (int r = 0; r < 4; ++r) red[wv][qd * 4 + r] = 1.0f / l_r[r];
  }
  asm volatile("s_waitcnt lgkmcnt(0)" ::: "memory");
  const float inv = red[wv][s];
#pragma unroll
  for (int ct = 0; ct < 16; ++ct) {
#pragma unroll
    for (int r = 0; r < 4; ++r) {
      const int c = ct * 16 + qd * 4 + r;
      ob[(size_t)c * kN + n0w + s] = acc[ct][r] * inv;
    }
  }
}

}  // namespace

extern "C" void kernel_launch(void* const* d_in, const int* in_sizes, int n_in,
                              void* d_out, int out_size, void* d_ws, size_t ws_size,
                              hipStream_t stream) {
  (void)in_sizes; (void)n_in; (void)d_ws; (void)ws_size; (void)out_size;
  const float* k = (const float*)d_in[0];
  const float* q = (const float*)d_in[1];
  const float* v = (const float*)d_in[2];
  float* out = (float*)d_out;
  dim3 grid(kB * (kN / QBLK));  // 256 blocks, ~1 per CU
  dim3 block(256);              // 4 waves
  hipLaunchKernelGGL(attn_fwd, grid, block, 0, stream, k, q, v, out);
}